// Round 11
// baseline (172.359 us; speedup 1.0000x reference)
//
#include <hip/hip_runtime.h>
#include <hip/hip_bf16.h>
#include <cmath>

// Problem constants (match reference)
constexpr int BB_ = 2;
constexpr int T_  = 1024;
constexpr int E_  = 1024;
constexpr int H_  = 8;
constexpr int HD_ = 128;
constexpr int WS_ = 64;
constexpr float TAU_   = 10.0f;
constexpr float SCALE_ = 0.08838834764831843f;  // 1/sqrt(128)

typedef __attribute__((ext_vector_type(8))) _Float16 half8;
typedef __attribute__((ext_vector_type(4))) _Float16 half4;
typedef __attribute__((ext_vector_type(2))) _Float16 half2v;
typedef __attribute__((ext_vector_type(4))) float floatx4;

// ---------------------------------------------------------------------------
// Kernel 1 (combo): blocks 0..127  = stable argsort (rank counting) + fused
//   gather h -> sorted-domain Ah (fp16, converted ONCE per row — R10 did this
//   48x redundantly inside the QKV GEMM).
// blocks 128..  = weight fp32 -> fp16 convert (4 matrices).
// ---------------------------------------------------------------------------
constexpr int STB_ = 16;          // t-values per sort block
constexpr int SORTB_ = BB_ * (T_ / STB_);   // 128 sort blocks
constexpr int WCONVB_ = (E_ * E_) / (256 * 8);  // 512 blocks per matrix

struct ComboArgs {
  const float* coord;
  const float* h;
  int* sidx;
  float* c_s;
  int* depot;
  _Float16* Ah;
  const float* wsrc[4];
  _Float16* wdst[4];
};

__global__ __launch_bounds__(256) void combo_prep_kernel(ComboArgs a) {
  __shared__ float c[T_];
  __shared__ int rnk[STB_];
  const int tid = threadIdx.x;

  if (blockIdx.x < SORTB_) {
    // ---- sort part ----
    const int nb = T_ / STB_;
    const int b = blockIdx.x / nb;
    const int t0 = (blockIdx.x % nb) * STB_;
    const float* cb = a.coord + (size_t)b * T_;
    for (int i = tid; i < T_; i += 256) c[i] = cb[i];
    __syncthreads();
    const int tl = tid >> 4;
    const int ch = tid & 15;
    const int t = t0 + tl;
    const float ct = c[t];
    int rank = 0;
    const int u0 = ch * (T_ / 16);
    #pragma unroll 8
    for (int i = 0; i < T_ / 16; ++i) {
      const int u = u0 + i;
      const float cu = c[u];
      rank += (cu < ct) || (cu == ct && u < t);
    }
    #pragma unroll
    for (int o = 8; o > 0; o >>= 1) rank += __shfl_xor(rank, o);
    if (ch == 0) {
      a.sidx[b * T_ + rank] = t;
      a.c_s[b * T_ + rank] = ct;
      rnk[tl] = rank;
      if (t == 0) a.depot[b] = rank;
    }
    __syncthreads();
    // ---- fused gather + fp16 convert: h[b][t0+r] -> Ah[b][rnk[r]] ----
    #pragma unroll 4
    for (int r = 0; r < STB_; ++r) {
      const float4 v =
          *(const float4*)(a.h + ((size_t)b * T_ + t0 + r) * E_ + tid * 4);
      half4 hv;
      hv.x = (_Float16)v.x; hv.y = (_Float16)v.y;
      hv.z = (_Float16)v.z; hv.w = (_Float16)v.w;
      *(half4*)(a.Ah + ((size_t)b * T_ + rnk[r]) * E_ + tid * 4) = hv;
    }
  } else {
    // ---- weight convert part: 8 elems per thread ----
    const int wb = blockIdx.x - SORTB_;
    const int z = wb / WCONVB_;
    const int chunk = wb - z * WCONVB_;
    const size_t idx = ((size_t)chunk * 256 + tid) * 8;
    const float4 v0 = *(const float4*)(a.wsrc[z] + idx);
    const float4 v1 = *(const float4*)(a.wsrc[z] + idx + 4);
    half8 hv;
    hv[0] = (_Float16)v0.x; hv[1] = (_Float16)v0.y;
    hv[2] = (_Float16)v0.z; hv[3] = (_Float16)v0.w;
    hv[4] = (_Float16)v1.x; hv[5] = (_Float16)v1.y;
    hv[6] = (_Float16)v1.z; hv[7] = (_Float16)v1.w;
    *(half8*)(a.wdst[z] + idx) = hv;
  }
}

// ---------------------------------------------------------------------------
// Kernel 2: fp16 MFMA GEMM.  A fp16 (sorted domain), W fp16.
//   FP16OUT: store fp16 (Q/K/V); else fp32. SCATTER: un-sort row scatter.
// Tile BM x BN, BK=32, 4 waves 2x2.
// ---------------------------------------------------------------------------
struct GemmArgs {
  const _Float16* W[3];
  const float* bias[3];
  float* Cf[3];
  _Float16* Ch[3];
};

constexpr int LP_ = 56;  // padded LDS row stride (halves): 112 B

template <int BM, int BN, int SCATTER, int FP16OUT>
__global__ __launch_bounds__(256, 2) void gemm_f16(
    GemmArgs args, const _Float16* __restrict__ A,
    const int* __restrict__ sidx) {
  constexpr int TMI = BM / 32;
  constexpr int TNI = BN / 32;
  const _Float16* __restrict__ W = args.W[blockIdx.z];
  const float* __restrict__ bias = args.bias[blockIdx.z];

  __shared__ _Float16 As[BM][LP_], Bs[BN][LP_];

  const int tid = threadIdx.x;
  const int wv = tid >> 6, lane = tid & 63;
  const int kq = lane >> 4, ln15 = lane & 15;
  const int wm0 = (wv >> 1) * (BM / 2), wn0 = (wv & 1) * (BN / 2);
  const int m0 = blockIdx.y * BM, n0 = blockIdx.x * BN;

  floatx4 acc[TMI][TNI];
  #pragma unroll
  for (int i = 0; i < TMI; ++i)
    #pragma unroll
    for (int j = 0; j < TNI; ++j) acc[i][j] = (floatx4){0.f, 0.f, 0.f, 0.f};

  for (int k0 = 0; k0 < E_; k0 += 32) {
    #pragma unroll
    for (int i = 0; i < BM * 4 / 256; ++i) {
      const int idx = tid + 256 * i;
      const int r = idx >> 2, c = idx & 3;
      *(half8*)&As[r][c * 8] =
          *(const half8*)(A + (size_t)(m0 + r) * E_ + k0 + c * 8);
    }
    #pragma unroll
    for (int i = 0; i < BN * 4 / 256; ++i) {
      const int idx = tid + 256 * i;
      const int r = idx >> 2, c = idx & 3;
      *(half8*)&Bs[r][c * 8] =
          *(const half8*)(W + (size_t)(n0 + r) * E_ + k0 + c * 8);
    }
    __syncthreads();

    half8 ah[TMI], bf[TNI];
    #pragma unroll
    for (int mi = 0; mi < TMI; ++mi)
      ah[mi] = *(const half8*)&As[wm0 + mi * 16 + ln15][kq * 8];
    #pragma unroll
    for (int ni = 0; ni < TNI; ++ni)
      bf[ni] = *(const half8*)&Bs[wn0 + ni * 16 + ln15][kq * 8];
    #pragma unroll
    for (int mi = 0; mi < TMI; ++mi)
      #pragma unroll
      for (int ni = 0; ni < TNI; ++ni)
        acc[mi][ni] = __builtin_amdgcn_mfma_f32_16x16x32_f16(
            ah[mi], bf[ni], acc[mi][ni], 0, 0, 0);
    __syncthreads();
  }

  float* __restrict__ Cf = args.Cf[blockIdx.z];
  _Float16* __restrict__ Ch = args.Ch[blockIdx.z];
  #pragma unroll
  for (int ni = 0; ni < TNI; ++ni) {
    const int col = n0 + wn0 + ni * 16 + ln15;
    const float bv = bias[col];
    #pragma unroll
    for (int mi = 0; mi < TMI; ++mi) {
      #pragma unroll
      for (int r = 0; r < 4; ++r) {
        const int m = m0 + wm0 + mi * 16 + kq * 4 + r;
        const int orow = SCATTER ? ((m & ~(T_ - 1)) + sidx[m]) : m;
        const float val = acc[mi][ni][r] + bv;
        if (FP16OUT) {
          Ch[(size_t)orow * E_ + col] = (_Float16)val;
        } else {
          Cf[(size_t)orow * E_ + col] = val;
        }
      }
    }
  }
}

// ---------------------------------------------------------------------------
// Kernel 3: local sliding-window attention — fp16 MFMA QK^T + slot-unified PV
// + fused depot-row scores (each block computes Q[dep].K[k] for its 16 keys).
// ---------------------------------------------------------------------------
constexpr int QTm_ = 16;
constexpr int NSL_ = 80;
constexpr int VSP_ = 8;

__global__ __launch_bounds__(256) void attn_local_kernel(
    const _Float16* __restrict__ Qh, const _Float16* __restrict__ Kh,
    const _Float16* __restrict__ Vh, const float* __restrict__ c_s,
    const int* __restrict__ depot, _Float16* __restrict__ CTh,
    float* __restrict__ scg) {
  __shared__ float sc[QTm_][88];    // [query][slot]; slot 80 = depot
  __shared__ float cw[NSL_];
  __shared__ float cq[QTm_];
  __shared__ float kdep[HD_];
  __shared__ float qdep[HD_];

  const int tid = threadIdx.x;
  const int ntq = T_ / QTm_;                 // 64
  const int tq = blockIdx.x % ntq;
  const int bh = blockIdx.x / ntq;
  const int h = bh % H_, b = bh / H_;
  const int t0 = tq * QTm_;
  const int dep = depot[b];
  const int smin = min(max(t0 - 32, 0), T_ - WS_);
  const size_t baseBH = ((size_t)b * T_) * E_ + (size_t)h * HD_;

  if (tid < NSL_) {
    cw[tid] = c_s[b * T_ + min(smin + tid, T_ - 1)];
  } else if (tid < NSL_ + QTm_) {
    cq[tid - NSL_] = c_s[b * T_ + t0 + tid - NSL_];
  } else if (tid >= 128) {
    const int d = tid - 128;
    kdep[d] = (float)Kh[baseBH + (size_t)dep * E_ + d];
  }
  if (tid < HD_) qdep[tid] = (float)Qh[baseBH + (size_t)dep * E_ + tid];
  __syncthreads();

  const int wv = tid >> 6, lane = tid & 63;
  const int ln15 = lane & 15, kq = lane >> 4;

  // ---- MFMA scores: wave w covers key tiles {w} (+ tile 4 for wave 0) ----
  {
    const size_t qoff = baseBH + (size_t)(t0 + ln15) * E_ + kq * 8;
    half8 aH[4];
    #pragma unroll
    for (int ks = 0; ks < 4; ++ks)
      aH[ks] = *(const half8*)(Qh + qoff + ks * 32);
    for (int kt = wv; kt < 5; kt += 4) {
      const int key = min(smin + kt * 16 + ln15, T_ - 1);
      const size_t koff = baseBH + (size_t)key * E_ + kq * 8;
      floatx4 acc = (floatx4){0.f, 0.f, 0.f, 0.f};
      #pragma unroll
      for (int ks = 0; ks < 4; ++ks) {
        const half8 b8 = *(const half8*)(Kh + koff + ks * 32);
        acc = __builtin_amdgcn_mfma_f32_16x16x32_f16(aH[ks], b8, acc, 0, 0, 0);
      }
      #pragma unroll
      for (int r = 0; r < 4; ++r)
        sc[kq * 4 + r][kt * 16 + ln15] = acc[r];
    }
  }

  const float cdep = c_s[b * T_ + dep];

  // ---- depot column raw scores (vector dot; wave handles 4 queries) ----
  #pragma unroll
  for (int qi = 0; qi < 4; ++qi) {
    const int q = wv * 4 + qi;
    const int t = t0 + q;
    const size_t qo2 = baseBH + (size_t)t * E_;
    const float q1 = (float)Qh[qo2 + lane];
    const float q2 = (float)Qh[qo2 + 64 + lane];
    float part = fmaf(q1, kdep[lane], q2 * kdep[lane + 64]);
    #pragma unroll
    for (int o = 32; o > 0; o >>= 1) part += __shfl_xor(part, o);
    if (lane == 0) {
      const int st = min(max(t - 32, 0), T_ - WS_);
      const bool masked = (unsigned)(dep - st) < (unsigned)WS_;
      const float dd = cdep - cq[q];
      sc[q][80] = masked ? -3.0e38f
                         : part * SCALE_ - dd * dd * (1.0f / TAU_);
    }
  }

  // ---- fused depot-row scores: keys [t0, t0+16) vs Q[dep] -> scg ----
  #pragma unroll
  for (int qi = 0; qi < 4; ++qi) {
    const int k = t0 + wv * 4 + qi;
    const size_t ko = baseBH + (size_t)k * E_;
    const float k1 = (float)Kh[ko + lane];
    const float k2 = (float)Kh[ko + 64 + lane];
    float part = fmaf(qdep[lane], k1, qdep[lane + 64] * k2);
    #pragma unroll
    for (int o = 32; o > 0; o >>= 1) part += __shfl_xor(part, o);
    if (lane == 0) {
      const float dd = cw[k - smin] - cdep;
      scg[bh * T_ + k] = part * SCALE_ - dd * dd * (1.0f / TAU_);
    }
  }
  __syncthreads();

  // ---- softmax (wave handles 4 queries); invalid slots get weight 0 ----
  #pragma unroll
  for (int qi = 0; qi < 4; ++qi) {
    const int q = wv * 4 + qi;
    const int t = t0 + q;
    const int st = min(max(t - 32, 0), T_ - WS_);
    const int base = st - smin;            // 0..16
    const float cqv = cq[q];
    const int j1 = lane;
    float s1 = -3.0e38f;
    if (j1 >= base && j1 < base + WS_) {
      const float dd = cw[j1] - cqv;
      s1 = sc[q][j1] * SCALE_ - dd * dd * (1.0f / TAU_);
    }
    const int j2 = 64 + lane;
    float s2 = -3.0e38f;
    if (lane < 16 && j2 >= base && j2 < base + WS_) {
      const float dd = cw[j2] - cqv;
      s2 = sc[q][j2] * SCALE_ - dd * dd * (1.0f / TAU_);
    }
    const float sdep = sc[q][80];
    float m = fmaxf(s1, s2);
    #pragma unroll
    for (int o = 32; o > 0; o >>= 1) m = fmaxf(m, __shfl_xor(m, o));
    m = fmaxf(m, sdep);
    const float e1 = expf(s1 - m);
    const float e2 = (lane < 16) ? expf(s2 - m) : 0.f;
    float sum = e1 + e2;
    #pragma unroll
    for (int o = 32; o > 0; o >>= 1) sum += __shfl_xor(sum, o);
    const float edep = expf(sdep - m);
    sum += edep;
    const float inv = 1.0f / sum;
    sc[q][j1] = e1 * inv;
    if (lane < 16) sc[q][j2] = e2 * inv;
    if (lane == 0) sc[q][80] = edep * inv;
  }
  __syncthreads();

  // ---- PV: one pass over 81 slots; V loaded as half2 per (slot, lane) ----
  {
    const int dp = lane * 2;          // dims dp, dp+1
    float acc0[4], acc1[4];
    #pragma unroll
    for (int qi = 0; qi < 4; ++qi) { acc0[qi] = 0.f; acc1[qi] = 0.f; }
    for (int j = 0; j <= NSL_; ++j) {
      const int row = (j < NSL_) ? min(smin + j, T_ - 1) : dep;
      const half2v v = *(const half2v*)(Vh + baseBH + (size_t)row * E_ + dp);
      const float v1 = (float)v.x;
      const float v2 = (float)v.y;
      #pragma unroll
      for (int qi = 0; qi < 4; ++qi) {
        const float w = sc[wv * 4 + qi][j];
        acc0[qi] = fmaf(w, v1, acc0[qi]);
        acc1[qi] = fmaf(w, v2, acc1[qi]);
      }
    }
    #pragma unroll
    for (int qi = 0; qi < 4; ++qi) {
      const int t = t0 + wv * 4 + qi;
      half2v o;
      o.x = (_Float16)acc0[qi];
      o.y = (_Float16)acc1[qi];
      *(half2v*)(CTh + baseBH + (size_t)t * E_ + dp) = o;
    }
  }
}

// ---------------------------------------------------------------------------
// Kernel 4: depot ctx with fused softmax. 128 blocks (b,h,split).
// ---------------------------------------------------------------------------
__global__ __launch_bounds__(256) void depot_ctx_kernel(
    const _Float16* __restrict__ Vh, const float* __restrict__ scg,
    float* __restrict__ part) {
  __shared__ float sc[T_];
  __shared__ float red[4];
  __shared__ float par[2][HD_];
  const int sp = blockIdx.x % VSP_;
  const int bh = blockIdx.x / VSP_;
  const int h = bh % H_, b = bh / H_;
  const int tid = threadIdx.x, wv = tid >> 6, lane = tid & 63;
  const float* s = scg + bh * T_;

  float lm = -3.0e38f;
  for (int k = tid; k < T_; k += 256) { sc[k] = s[k]; lm = fmaxf(lm, sc[k]); }
  #pragma unroll
  for (int o = 32; o > 0; o >>= 1) lm = fmaxf(lm, __shfl_xor(lm, o));
  if (lane == 0) red[wv] = lm;
  __syncthreads();
  const float M = fmaxf(fmaxf(red[0], red[1]), fmaxf(red[2], red[3]));
  __syncthreads();
  float ls = 0.f;
  float ev[T_ / 256];
  #pragma unroll
  for (int i = 0; i < T_ / 256; ++i) {
    ev[i] = expf(sc[tid + 256 * i] - M);
    ls += ev[i];
  }
  #pragma unroll
  for (int o = 32; o > 0; o >>= 1) ls += __shfl_xor(ls, o);
  if (lane == 0) red[wv] = ls;
  __syncthreads();
  const float inv = 1.0f / (red[0] + red[1] + red[2] + red[3]);
  #pragma unroll
  for (int i = 0; i < T_ / 256; ++i) sc[tid + 256 * i] = ev[i] * inv;
  __syncthreads();

  const int d = tid & 127, kg = tid >> 7;
  const size_t baseBH = ((size_t)b * T_) * E_ + (size_t)h * HD_;
  constexpr int KPB = T_ / VSP_;
  const int k0 = sp * KPB + kg * (KPB / 2);
  const _Float16* vbase = Vh + baseBH + d;
  float acc = 0.f;
  #pragma unroll 8
  for (int k = k0; k < k0 + KPB / 2; ++k) {
    acc = fmaf(sc[k], (float)vbase[(size_t)k * E_], acc);
  }
  par[kg][d] = acc;
  __syncthreads();
  if (tid < HD_) part[((size_t)sp * BB_ * H_ + bh) * HD_ + tid] =
      par[0][tid] + par[1][tid];
}

// ---------------------------------------------------------------------------
// Kernel 5: reduce depot splits, write depot ctx rows. 1 block.
// ---------------------------------------------------------------------------
__global__ __launch_bounds__(256) void depot_write_kernel(
    const float* __restrict__ part, const int* __restrict__ depot,
    _Float16* __restrict__ CTh) {
  for (int o = threadIdx.x; o < BB_ * H_ * HD_; o += 256) {
    const int bh = o >> 7, d = o & 127;
    float s = 0.f;
    #pragma unroll
    for (int sp = 0; sp < VSP_; ++sp)
      s += part[((size_t)sp * BB_ * H_ + bh) * HD_ + d];
    const int h = bh % H_, b = bh / H_;
    const int dep = depot[b];
    CTh[((size_t)b * T_ + dep) * E_ + (size_t)h * HD_ + d] = (_Float16)s;
  }
}

// ---------------------------------------------------------------------------
extern "C" void kernel_launch(void* const* d_in, const int* in_sizes, int n_in,
                              void* d_out, int out_size, void* d_ws, size_t ws_size,
                              hipStream_t stream) {
  const float* h     = (const float*)d_in[0];
  const float* coord = (const float*)d_in[1];
  const float* Wq    = (const float*)d_in[2];
  const float* Wqb   = (const float*)d_in[3];
  const float* Wk    = (const float*)d_in[4];
  const float* Wkb   = (const float*)d_in[5];
  const float* Wv    = (const float*)d_in[6];
  const float* Wvb   = (const float*)d_in[7];
  const float* Wo    = (const float*)d_in[8];
  const float* Wob   = (const float*)d_in[9];
  float* out = (float*)d_out;

  char* ws = (char*)d_ws;
  const size_t MATH_ = (size_t)BB_ * T_ * E_ * 2;  // 4 MB fp16
  const size_t WB   = (size_t)E_ * E_ * 2;         // 2 MB fp16
  size_t off = 0;
  _Float16* Qh  = (_Float16*)(ws + off); off += MATH_;
  _Float16* Kh  = (_Float16*)(ws + off); off += MATH_;
  _Float16* Vh  = (_Float16*)(ws + off); off += MATH_;
  _Float16* Ah  = (_Float16*)(ws + off); off += MATH_;
  _Float16* CTh = (_Float16*)(ws + off); off += MATH_;
  _Float16* Wh[4];
  for (int i = 0; i < 4; ++i) { Wh[i] = (_Float16*)(ws + off); off += WB; }
  float* c_s = (float*)(ws + off); off += (size_t)BB_ * T_ * 4;
  int* sidx  = (int*)(ws + off);   off += (size_t)BB_ * T_ * 4;
  int* depo  = (int*)(ws + off);   off += 256;
  float* scg  = (float*)(ws + off); off += (size_t)BB_ * H_ * T_ * 4;
  float* dpar = (float*)(ws + off); off += (size_t)VSP_ * BB_ * H_ * HD_ * 4;

  // 1. combo: sort + gather/convert h (once) + weight converts
  ComboArgs ca;
  ca.coord = coord; ca.h = h; ca.sidx = sidx; ca.c_s = c_s;
  ca.depot = depo; ca.Ah = Ah;
  ca.wsrc[0] = Wq; ca.wsrc[1] = Wk; ca.wsrc[2] = Wv; ca.wsrc[3] = Wo;
  for (int i = 0; i < 4; ++i) ca.wdst[i] = Wh[i];
  combo_prep_kernel<<<SORTB_ + 4 * WCONVB_, 256, 0, stream>>>(ca);

  // 2. QKV projections (fp16 A, already sorted/gathered); fp16 out
  GemmArgs qa;
  qa.W[0] = Wh[0]; qa.W[1] = Wh[1]; qa.W[2] = Wh[2];
  qa.bias[0] = Wqb; qa.bias[1] = Wkb; qa.bias[2] = Wvb;
  qa.Cf[0] = qa.Cf[1] = qa.Cf[2] = nullptr;
  qa.Ch[0] = Qh; qa.Ch[1] = Kh; qa.Ch[2] = Vh;
  gemm_f16<128, 64, 0, 1><<<dim3(E_ / 64, (BB_ * T_) / 128, 3), 256, 0, stream>>>(
      qa, Ah, sidx);

  // 3. sliding-window attention + fused depot-row scores
  attn_local_kernel<<<BB_ * H_ * (T_ / QTm_), 256, 0, stream>>>(
      Qh, Kh, Vh, c_s, depo, CTh, scg);

  // 4. depot ctx (fused softmax), then split-reduce + write
  depot_ctx_kernel<<<BB_ * H_ * VSP_, 256, 0, stream>>>(Vh, scg, dpar);
  depot_write_kernel<<<1, 256, 0, stream>>>(dpar, depo, CTh);

  // 5. output projection; fp32 out, fused un-sort scatter
  GemmArgs oa;
  oa.W[0] = oa.W[1] = oa.W[2] = Wh[3];
  oa.bias[0] = oa.bias[1] = oa.bias[2] = Wob;
  oa.Cf[0] = oa.Cf[1] = oa.Cf[2] = out;
  oa.Ch[0] = oa.Ch[1] = oa.Ch[2] = nullptr;
  gemm_f16<64, 64, 1, 0><<<dim3(E_ / 64, (BB_ * T_) / 64, 1), 256, 0, stream>>>(
      oa, CTh, sidx);
}

// Round 12
// 164.861 us; speedup vs baseline: 1.0455x; 1.0455x over previous
//
#include <hip/hip_runtime.h>
#include <hip/hip_bf16.h>
#include <cmath>

// Problem constants (match reference)
constexpr int BB_ = 2;
constexpr int T_  = 1024;
constexpr int E_  = 1024;
constexpr int H_  = 8;
constexpr int HD_ = 128;
constexpr int WS_ = 64;
constexpr float TAU_   = 10.0f;
constexpr float SCALE_ = 0.08838834764831843f;  // 1/sqrt(128)

typedef __attribute__((ext_vector_type(8))) _Float16 half8;
typedef __attribute__((ext_vector_type(4))) _Float16 half4;
typedef __attribute__((ext_vector_type(2))) _Float16 half2v;
typedef __attribute__((ext_vector_type(4))) float floatx4;

// ---------------------------------------------------------------------------
// Kernel 1 (combo): blocks 0..127  = stable argsort (rank counting) + fused
//   gather h -> sorted-domain Ah (fp16, converted once per row).
// blocks 128..  = weight fp32 -> fp16 convert (4 matrices).
// ---------------------------------------------------------------------------
constexpr int STB_ = 16;          // t-values per sort block
constexpr int SORTB_ = BB_ * (T_ / STB_);   // 128 sort blocks
constexpr int WCONVB_ = (E_ * E_) / (256 * 8);  // 512 blocks per matrix

struct ComboArgs {
  const float* coord;
  const float* h;
  int* sidx;
  float* c_s;
  int* depot;
  _Float16* Ah;
  const float* wsrc[4];
  _Float16* wdst[4];
};

__global__ __launch_bounds__(256) void combo_prep_kernel(ComboArgs a) {
  __shared__ float c[T_];
  __shared__ int rnk[STB_];
  const int tid = threadIdx.x;

  if (blockIdx.x < SORTB_) {
    // ---- sort part ----
    const int nb = T_ / STB_;
    const int b = blockIdx.x / nb;
    const int t0 = (blockIdx.x % nb) * STB_;
    const float* cb = a.coord + (size_t)b * T_;
    for (int i = tid; i < T_; i += 256) c[i] = cb[i];
    __syncthreads();
    const int tl = tid >> 4;
    const int ch = tid & 15;
    const int t = t0 + tl;
    const float ct = c[t];
    int rank = 0;
    const int u0 = ch * (T_ / 16);
    #pragma unroll 8
    for (int i = 0; i < T_ / 16; ++i) {
      const int u = u0 + i;
      const float cu = c[u];
      rank += (cu < ct) || (cu == ct && u < t);
    }
    #pragma unroll
    for (int o = 8; o > 0; o >>= 1) rank += __shfl_xor(rank, o);
    if (ch == 0) {
      a.sidx[b * T_ + rank] = t;
      a.c_s[b * T_ + rank] = ct;
      rnk[tl] = rank;
      if (t == 0) a.depot[b] = rank;
    }
    __syncthreads();
    // ---- fused gather + fp16 convert: h[b][t0+r] -> Ah[b][rnk[r]] ----
    #pragma unroll 4
    for (int r = 0; r < STB_; ++r) {
      const float4 v =
          *(const float4*)(a.h + ((size_t)b * T_ + t0 + r) * E_ + tid * 4);
      half4 hv;
      hv.x = (_Float16)v.x; hv.y = (_Float16)v.y;
      hv.z = (_Float16)v.z; hv.w = (_Float16)v.w;
      *(half4*)(a.Ah + ((size_t)b * T_ + rnk[r]) * E_ + tid * 4) = hv;
    }
  } else {
    // ---- weight convert part: 8 elems per thread ----
    const int wb = blockIdx.x - SORTB_;
    const int z = wb / WCONVB_;
    const int chunk = wb - z * WCONVB_;
    const size_t idx = ((size_t)chunk * 256 + tid) * 8;
    const float4 v0 = *(const float4*)(a.wsrc[z] + idx);
    const float4 v1 = *(const float4*)(a.wsrc[z] + idx + 4);
    half8 hv;
    hv[0] = (_Float16)v0.x; hv[1] = (_Float16)v0.y;
    hv[2] = (_Float16)v0.z; hv[3] = (_Float16)v0.w;
    hv[4] = (_Float16)v1.x; hv[5] = (_Float16)v1.y;
    hv[6] = (_Float16)v1.z; hv[7] = (_Float16)v1.w;
    *(half8*)(a.wdst[z] + idx) = hv;
  }
}

// ---------------------------------------------------------------------------
// Kernel 2: fp16 MFMA GEMM.  A fp16 (sorted domain), W fp16.
//   FP16OUT: store fp16 (Q/K/V); else fp32. SCATTER: un-sort row scatter.
// Tile BM x BN, BK=32, 4 waves 2x2, wave tile (BM/2)x(BN/2).
// QKV uses 128x128 (wave tile 64x64): 8 ds_read_b128 per K32 for 131072 MACs
// — 1.5x better LDS-reuse than the old 128x64 (6 reads / 65536 MACs).
// ---------------------------------------------------------------------------
struct GemmArgs {
  const _Float16* W[3];
  const float* bias[3];
  float* Cf[3];
  _Float16* Ch[3];
};

constexpr int LP_ = 56;  // padded LDS row stride (halves): 112 B

template <int BM, int BN, int SCATTER, int FP16OUT>
__global__ __launch_bounds__(256, 2) void gemm_f16(
    GemmArgs args, const _Float16* __restrict__ A,
    const int* __restrict__ sidx) {
  constexpr int TMI = BM / 32;
  constexpr int TNI = BN / 32;
  const _Float16* __restrict__ W = args.W[blockIdx.z];
  const float* __restrict__ bias = args.bias[blockIdx.z];

  __shared__ _Float16 As[BM][LP_], Bs[BN][LP_];

  const int tid = threadIdx.x;
  const int wv = tid >> 6, lane = tid & 63;
  const int kq = lane >> 4, ln15 = lane & 15;
  const int wm0 = (wv >> 1) * (BM / 2), wn0 = (wv & 1) * (BN / 2);
  const int m0 = blockIdx.y * BM, n0 = blockIdx.x * BN;

  floatx4 acc[TMI][TNI];
  #pragma unroll
  for (int i = 0; i < TMI; ++i)
    #pragma unroll
    for (int j = 0; j < TNI; ++j) acc[i][j] = (floatx4){0.f, 0.f, 0.f, 0.f};

  for (int k0 = 0; k0 < E_; k0 += 32) {
    #pragma unroll
    for (int i = 0; i < BM * 4 / 256; ++i) {
      const int idx = tid + 256 * i;
      const int r = idx >> 2, c = idx & 3;
      *(half8*)&As[r][c * 8] =
          *(const half8*)(A + (size_t)(m0 + r) * E_ + k0 + c * 8);
    }
    #pragma unroll
    for (int i = 0; i < BN * 4 / 256; ++i) {
      const int idx = tid + 256 * i;
      const int r = idx >> 2, c = idx & 3;
      *(half8*)&Bs[r][c * 8] =
          *(const half8*)(W + (size_t)(n0 + r) * E_ + k0 + c * 8);
    }
    __syncthreads();

    half8 ah[TMI], bf[TNI];
    #pragma unroll
    for (int mi = 0; mi < TMI; ++mi)
      ah[mi] = *(const half8*)&As[wm0 + mi * 16 + ln15][kq * 8];
    #pragma unroll
    for (int ni = 0; ni < TNI; ++ni)
      bf[ni] = *(const half8*)&Bs[wn0 + ni * 16 + ln15][kq * 8];
    #pragma unroll
    for (int mi = 0; mi < TMI; ++mi)
      #pragma unroll
      for (int ni = 0; ni < TNI; ++ni)
        acc[mi][ni] = __builtin_amdgcn_mfma_f32_16x16x32_f16(
            ah[mi], bf[ni], acc[mi][ni], 0, 0, 0);
    __syncthreads();
  }

  float* __restrict__ Cf = args.Cf[blockIdx.z];
  _Float16* __restrict__ Ch = args.Ch[blockIdx.z];
  #pragma unroll
  for (int ni = 0; ni < TNI; ++ni) {
    const int col = n0 + wn0 + ni * 16 + ln15;
    const float bv = bias[col];
    #pragma unroll
    for (int mi = 0; mi < TMI; ++mi) {
      #pragma unroll
      for (int r = 0; r < 4; ++r) {
        const int m = m0 + wm0 + mi * 16 + kq * 4 + r;
        const int orow = SCATTER ? ((m & ~(T_ - 1)) + sidx[m]) : m;
        const float val = acc[mi][ni][r] + bv;
        if (FP16OUT) {
          Ch[(size_t)orow * E_ + col] = (_Float16)val;
        } else {
          Cf[(size_t)orow * E_ + col] = val;
        }
      }
    }
  }
}

// ---------------------------------------------------------------------------
// Kernel 3: local sliding-window attention — fp16 MFMA QK^T + slot-unified PV
// + fused depot-row scores (each block computes Q[dep].K[k] for its 16 keys).
// ---------------------------------------------------------------------------
constexpr int QTm_ = 16;
constexpr int NSL_ = 80;
constexpr int VSP_ = 8;

__global__ __launch_bounds__(256) void attn_local_kernel(
    const _Float16* __restrict__ Qh, const _Float16* __restrict__ Kh,
    const _Float16* __restrict__ Vh, const float* __restrict__ c_s,
    const int* __restrict__ depot, _Float16* __restrict__ CTh,
    float* __restrict__ scg) {
  __shared__ float sc[QTm_][88];    // [query][slot]; slot 80 = depot
  __shared__ float cw[NSL_];
  __shared__ float cq[QTm_];
  __shared__ float kdep[HD_];
  __shared__ float qdep[HD_];

  const int tid = threadIdx.x;
  const int ntq = T_ / QTm_;                 // 64
  const int tq = blockIdx.x % ntq;
  const int bh = blockIdx.x / ntq;
  const int h = bh % H_, b = bh / H_;
  const int t0 = tq * QTm_;
  const int dep = depot[b];
  const int smin = min(max(t0 - 32, 0), T_ - WS_);
  const size_t baseBH = ((size_t)b * T_) * E_ + (size_t)h * HD_;

  if (tid < NSL_) {
    cw[tid] = c_s[b * T_ + min(smin + tid, T_ - 1)];
  } else if (tid < NSL_ + QTm_) {
    cq[tid - NSL_] = c_s[b * T_ + t0 + tid - NSL_];
  } else if (tid >= 128) {
    const int d = tid - 128;
    kdep[d] = (float)Kh[baseBH + (size_t)dep * E_ + d];
  }
  if (tid < HD_) qdep[tid] = (float)Qh[baseBH + (size_t)dep * E_ + tid];
  __syncthreads();

  const int wv = tid >> 6, lane = tid & 63;
  const int ln15 = lane & 15, kq = lane >> 4;

  // ---- MFMA scores: wave w covers key tiles {w} (+ tile 4 for wave 0) ----
  {
    const size_t qoff = baseBH + (size_t)(t0 + ln15) * E_ + kq * 8;
    half8 aH[4];
    #pragma unroll
    for (int ks = 0; ks < 4; ++ks)
      aH[ks] = *(const half8*)(Qh + qoff + ks * 32);
    for (int kt = wv; kt < 5; kt += 4) {
      const int key = min(smin + kt * 16 + ln15, T_ - 1);
      const size_t koff = baseBH + (size_t)key * E_ + kq * 8;
      floatx4 acc = (floatx4){0.f, 0.f, 0.f, 0.f};
      #pragma unroll
      for (int ks = 0; ks < 4; ++ks) {
        const half8 b8 = *(const half8*)(Kh + koff + ks * 32);
        acc = __builtin_amdgcn_mfma_f32_16x16x32_f16(aH[ks], b8, acc, 0, 0, 0);
      }
      #pragma unroll
      for (int r = 0; r < 4; ++r)
        sc[kq * 4 + r][kt * 16 + ln15] = acc[r];
    }
  }

  const float cdep = c_s[b * T_ + dep];

  // ---- depot column raw scores (vector dot; wave handles 4 queries) ----
  #pragma unroll
  for (int qi = 0; qi < 4; ++qi) {
    const int q = wv * 4 + qi;
    const int t = t0 + q;
    const size_t qo2 = baseBH + (size_t)t * E_;
    const float q1 = (float)Qh[qo2 + lane];
    const float q2 = (float)Qh[qo2 + 64 + lane];
    float part = fmaf(q1, kdep[lane], q2 * kdep[lane + 64]);
    #pragma unroll
    for (int o = 32; o > 0; o >>= 1) part += __shfl_xor(part, o);
    if (lane == 0) {
      const int st = min(max(t - 32, 0), T_ - WS_);
      const bool masked = (unsigned)(dep - st) < (unsigned)WS_;
      const float dd = cdep - cq[q];
      sc[q][80] = masked ? -3.0e38f
                         : part * SCALE_ - dd * dd * (1.0f / TAU_);
    }
  }

  // ---- fused depot-row scores: keys [t0, t0+16) vs Q[dep] -> scg ----
  #pragma unroll
  for (int qi = 0; qi < 4; ++qi) {
    const int k = t0 + wv * 4 + qi;
    const size_t ko = baseBH + (size_t)k * E_;
    const float k1 = (float)Kh[ko + lane];
    const float k2 = (float)Kh[ko + 64 + lane];
    float part = fmaf(qdep[lane], k1, qdep[lane + 64] * k2);
    #pragma unroll
    for (int o = 32; o > 0; o >>= 1) part += __shfl_xor(part, o);
    if (lane == 0) {
      const float dd = cw[k - smin] - cdep;
      scg[bh * T_ + k] = part * SCALE_ - dd * dd * (1.0f / TAU_);
    }
  }
  __syncthreads();

  // ---- softmax (wave handles 4 queries); invalid slots get weight 0 ----
  #pragma unroll
  for (int qi = 0; qi < 4; ++qi) {
    const int q = wv * 4 + qi;
    const int t = t0 + q;
    const int st = min(max(t - 32, 0), T_ - WS_);
    const int base = st - smin;            // 0..16
    const float cqv = cq[q];
    const int j1 = lane;
    float s1 = -3.0e38f;
    if (j1 >= base && j1 < base + WS_) {
      const float dd = cw[j1] - cqv;
      s1 = sc[q][j1] * SCALE_ - dd * dd * (1.0f / TAU_);
    }
    const int j2 = 64 + lane;
    float s2 = -3.0e38f;
    if (lane < 16 && j2 >= base && j2 < base + WS_) {
      const float dd = cw[j2] - cqv;
      s2 = sc[q][j2] * SCALE_ - dd * dd * (1.0f / TAU_);
    }
    const float sdep = sc[q][80];
    float m = fmaxf(s1, s2);
    #pragma unroll
    for (int o = 32; o > 0; o >>= 1) m = fmaxf(m, __shfl_xor(m, o));
    m = fmaxf(m, sdep);
    const float e1 = expf(s1 - m);
    const float e2 = (lane < 16) ? expf(s2 - m) : 0.f;
    float sum = e1 + e2;
    #pragma unroll
    for (int o = 32; o > 0; o >>= 1) sum += __shfl_xor(sum, o);
    const float edep = expf(sdep - m);
    sum += edep;
    const float inv = 1.0f / sum;
    sc[q][j1] = e1 * inv;
    if (lane < 16) sc[q][j2] = e2 * inv;
    if (lane == 0) sc[q][80] = edep * inv;
  }
  __syncthreads();

  // ---- PV: one pass over 81 slots; V loaded as half2 per (slot, lane) ----
  {
    const int dp = lane * 2;          // dims dp, dp+1
    float acc0[4], acc1[4];
    #pragma unroll
    for (int qi = 0; qi < 4; ++qi) { acc0[qi] = 0.f; acc1[qi] = 0.f; }
    for (int j = 0; j <= NSL_; ++j) {
      const int row = (j < NSL_) ? min(smin + j, T_ - 1) : dep;
      const half2v v = *(const half2v*)(Vh + baseBH + (size_t)row * E_ + dp);
      const float v1 = (float)v.x;
      const float v2 = (float)v.y;
      #pragma unroll
      for (int qi = 0; qi < 4; ++qi) {
        const float w = sc[wv * 4 + qi][j];
        acc0[qi] = fmaf(w, v1, acc0[qi]);
        acc1[qi] = fmaf(w, v2, acc1[qi]);
      }
    }
    #pragma unroll
    for (int qi = 0; qi < 4; ++qi) {
      const int t = t0 + wv * 4 + qi;
      half2v o;
      o.x = (_Float16)acc0[qi];
      o.y = (_Float16)acc1[qi];
      *(half2v*)(CTh + baseBH + (size_t)t * E_ + dp) = o;
    }
  }
}

// ---------------------------------------------------------------------------
// Kernel 4: depot ctx with fused softmax. 128 blocks (b,h,split).
// ---------------------------------------------------------------------------
__global__ __launch_bounds__(256) void depot_ctx_kernel(
    const _Float16* __restrict__ Vh, const float* __restrict__ scg,
    float* __restrict__ part) {
  __shared__ float sc[T_];
  __shared__ float red[4];
  __shared__ float par[2][HD_];
  const int sp = blockIdx.x % VSP_;
  const int bh = blockIdx.x / VSP_;
  const int h = bh % H_, b = bh / H_;
  const int tid = threadIdx.x, wv = tid >> 6, lane = tid & 63;
  const float* s = scg + bh * T_;

  float lm = -3.0e38f;
  for (int k = tid; k < T_; k += 256) { sc[k] = s[k]; lm = fmaxf(lm, sc[k]); }
  #pragma unroll
  for (int o = 32; o > 0; o >>= 1) lm = fmaxf(lm, __shfl_xor(lm, o));
  if (lane == 0) red[wv] = lm;
  __syncthreads();
  const float M = fmaxf(fmaxf(red[0], red[1]), fmaxf(red[2], red[3]));
  __syncthreads();
  float ls = 0.f;
  float ev[T_ / 256];
  #pragma unroll
  for (int i = 0; i < T_ / 256; ++i) {
    ev[i] = expf(sc[tid + 256 * i] - M);
    ls += ev[i];
  }
  #pragma unroll
  for (int o = 32; o > 0; o >>= 1) ls += __shfl_xor(ls, o);
  if (lane == 0) red[wv] = ls;
  __syncthreads();
  const float inv = 1.0f / (red[0] + red[1] + red[2] + red[3]);
  #pragma unroll
  for (int i = 0; i < T_ / 256; ++i) sc[tid + 256 * i] = ev[i] * inv;
  __syncthreads();

  const int d = tid & 127, kg = tid >> 7;
  const size_t baseBH = ((size_t)b * T_) * E_ + (size_t)h * HD_;
  constexpr int KPB = T_ / VSP_;
  const int k0 = sp * KPB + kg * (KPB / 2);
  const _Float16* vbase = Vh + baseBH + d;
  float acc = 0.f;
  #pragma unroll 8
  for (int k = k0; k < k0 + KPB / 2; ++k) {
    acc = fmaf(sc[k], (float)vbase[(size_t)k * E_], acc);
  }
  par[kg][d] = acc;
  __syncthreads();
  if (tid < HD_) part[((size_t)sp * BB_ * H_ + bh) * HD_ + tid] =
      par[0][tid] + par[1][tid];
}

// ---------------------------------------------------------------------------
// Kernel 5: reduce depot splits, write depot ctx rows. 1 block.
// ---------------------------------------------------------------------------
__global__ __launch_bounds__(256) void depot_write_kernel(
    const float* __restrict__ part, const int* __restrict__ depot,
    _Float16* __restrict__ CTh) {
  for (int o = threadIdx.x; o < BB_ * H_ * HD_; o += 256) {
    const int bh = o >> 7, d = o & 127;
    float s = 0.f;
    #pragma unroll
    for (int sp = 0; sp < VSP_; ++sp)
      s += part[((size_t)sp * BB_ * H_ + bh) * HD_ + d];
    const int h = bh % H_, b = bh / H_;
    const int dep = depot[b];
    CTh[((size_t)b * T_ + dep) * E_ + (size_t)h * HD_ + d] = (_Float16)s;
  }
}

// ---------------------------------------------------------------------------
extern "C" void kernel_launch(void* const* d_in, const int* in_sizes, int n_in,
                              void* d_out, int out_size, void* d_ws, size_t ws_size,
                              hipStream_t stream) {
  const float* h     = (const float*)d_in[0];
  const float* coord = (const float*)d_in[1];
  const float* Wq    = (const float*)d_in[2];
  const float* Wqb   = (const float*)d_in[3];
  const float* Wk    = (const float*)d_in[4];
  const float* Wkb   = (const float*)d_in[5];
  const float* Wv    = (const float*)d_in[6];
  const float* Wvb   = (const float*)d_in[7];
  const float* Wo    = (const float*)d_in[8];
  const float* Wob   = (const float*)d_in[9];
  float* out = (float*)d_out;

  char* ws = (char*)d_ws;
  const size_t MATH_ = (size_t)BB_ * T_ * E_ * 2;  // 4 MB fp16
  const size_t WB   = (size_t)E_ * E_ * 2;         // 2 MB fp16
  size_t off = 0;
  _Float16* Qh  = (_Float16*)(ws + off); off += MATH_;
  _Float16* Kh  = (_Float16*)(ws + off); off += MATH_;
  _Float16* Vh  = (_Float16*)(ws + off); off += MATH_;
  _Float16* Ah  = (_Float16*)(ws + off); off += MATH_;
  _Float16* CTh = (_Float16*)(ws + off); off += MATH_;
  _Float16* Wh[4];
  for (int i = 0; i < 4; ++i) { Wh[i] = (_Float16*)(ws + off); off += WB; }
  float* c_s = (float*)(ws + off); off += (size_t)BB_ * T_ * 4;
  int* sidx  = (int*)(ws + off);   off += (size_t)BB_ * T_ * 4;
  int* depo  = (int*)(ws + off);   off += 256;
  float* scg  = (float*)(ws + off); off += (size_t)BB_ * H_ * T_ * 4;
  float* dpar = (float*)(ws + off); off += (size_t)VSP_ * BB_ * H_ * HD_ * 4;

  // 1. combo: sort + gather/convert h (once) + weight converts
  ComboArgs ca;
  ca.coord = coord; ca.h = h; ca.sidx = sidx; ca.c_s = c_s;
  ca.depot = depo; ca.Ah = Ah;
  ca.wsrc[0] = Wq; ca.wsrc[1] = Wk; ca.wsrc[2] = Wv; ca.wsrc[3] = Wo;
  for (int i = 0; i < 4; ++i) ca.wdst[i] = Wh[i];
  combo_prep_kernel<<<SORTB_ + 4 * WCONVB_, 256, 0, stream>>>(ca);

  // 2. QKV projections: 128x128 tiles, wave tile 64x64 (1.5x LDS reuse)
  GemmArgs qa;
  qa.W[0] = Wh[0]; qa.W[1] = Wh[1]; qa.W[2] = Wh[2];
  qa.bias[0] = Wqb; qa.bias[1] = Wkb; qa.bias[2] = Wvb;
  qa.Cf[0] = qa.Cf[1] = qa.Cf[2] = nullptr;
  qa.Ch[0] = Qh; qa.Ch[1] = Kh; qa.Ch[2] = Vh;
  gemm_f16<128, 128, 0, 1><<<dim3(E_ / 128, (BB_ * T_) / 128, 3), 256, 0, stream>>>(
      qa, Ah, sidx);

  // 3. sliding-window attention + fused depot-row scores
  attn_local_kernel<<<BB_ * H_ * (T_ / QTm_), 256, 0, stream>>>(
      Qh, Kh, Vh, c_s, depo, CTh, scg);

  // 4. depot ctx (fused softmax), then split-reduce + write
  depot_ctx_kernel<<<BB_ * H_ * VSP_, 256, 0, stream>>>(Vh, scg, dpar);
  depot_write_kernel<<<1, 256, 0, stream>>>(dpar, depo, CTh);

  // 5. output projection; fp32 out, fused un-sort scatter
  GemmArgs oa;
  oa.W[0] = oa.W[1] = oa.W[2] = Wh[3];
  oa.bias[0] = oa.bias[1] = oa.bias[2] = Wob;
  oa.Cf[0] = oa.Cf[1] = oa.Cf[2] = out;
  oa.Ch[0] = oa.Ch[1] = oa.Ch[2] = nullptr;
  gemm_f16<64, 64, 1, 0><<<dim3(E_ / 64, (BB_ * T_) / 64, 1), 256, 0, stream>>>(
      oa, CTh, sidx);
}